// Round 1
// baseline (173.460 us; speedup 1.0000x reference)
//
#include <hip/hip_runtime.h>
#include <math.h>

#define NCLUST 32768
#define CLEN 256

// One wave (64 lanes) per cluster. Each lane owns 4 points (registers).
// Pass 1: gather + sums (center, mean/std of value, sem counts)
// Pass 2: covariance A (6 entries)
// Eigen: analytic symmetric-3x3 in double (redundant across lanes)
// Pass 3: sc = sum(x0 * |perp|) for the sign flip of v2
__global__ __launch_bounds__(64) void clust_geo_kernel(
    const float* __restrict__ data,      // N x 6
    const int*   __restrict__ clust_idx, // C x 256
    const int*   __restrict__ clust_len, // C
    float*       __restrict__ out)       // C x 19
{
    const int c    = blockIdx.x;
    const int lane = threadIdx.x;           // 0..63
    const int len  = clust_len[c];
    const float fn = (float)len;

    // 4 indices per lane, coalesced 16B load
    const int4 idx4 = ((const int4*)(clust_idx + (size_t)c * CLEN))[lane];
    const int idx[4] = {idx4.x, idx4.y, idx4.z, idx4.w};

    float px[4], py[4], pz[4];
    float sx = 0.f, sy = 0.f, sz = 0.f, sv = 0.f, sv2 = 0.f;
    int c0 = 0, c1 = 0, c2 = 0, c3 = 0, c4 = 0;

#pragma unroll
    for (int j = 0; j < 4; ++j) {
        const int l = lane * 4 + j;
        const bool ok = l < len;
        float x = 0.f, y = 0.f, z = 0.f, v = 0.f;
        int s = -1;
        if (ok) {
            const float* p = data + (size_t)idx[j] * 6;
            const float2 xy = *(const float2*)p;        // x, y
            const float  zz = p[2];                     // z
            const float2 vs = *(const float2*)(p + 4);  // value, sem
            x = xy.x; y = xy.y; z = zz; v = vs.x; s = (int)vs.y;
        }
        px[j] = x; py[j] = y; pz[j] = z;
        sx += x; sy += y; sz += z; sv += v; sv2 += v * v;
        c0 += (s == 0); c1 += (s == 1); c2 += (s == 2); c3 += (s == 3); c4 += (s == 4);
    }

    // butterfly reduce (all lanes end with totals)
#pragma unroll
    for (int off = 32; off >= 1; off >>= 1) {
        sx  += __shfl_xor(sx, off);
        sy  += __shfl_xor(sy, off);
        sz  += __shfl_xor(sz, off);
        sv  += __shfl_xor(sv, off);
        sv2 += __shfl_xor(sv2, off);
        c0  += __shfl_xor(c0, off);
        c1  += __shfl_xor(c1, off);
        c2  += __shfl_xor(c2, off);
        c3  += __shfl_xor(c3, off);
        c4  += __shfl_xor(c4, off);
    }

    const float inv_n = 1.0f / fn;
    const float cx = sx * inv_n, cy = sy * inv_n, cz = sz * inv_n;
    const float mean_v = sv * inv_n;
    const float var_v = (sv2 - fn * mean_v * mean_v) / (fn - 1.0f);
    const float std_v = sqrtf(fmaxf(var_v, 0.0f));

    // mode: first index of max (argmax tie-break = strict >)
    int mode = 0, best = c0;
    if (c1 > best) { best = c1; mode = 1; }
    if (c2 > best) { best = c2; mode = 2; }
    if (c3 > best) { best = c3; mode = 3; }
    if (c4 > best) { best = c4; mode = 4; }

    // Pass 2: covariance of centered, masked coords
    float a00 = 0.f, a01 = 0.f, a02 = 0.f, a11 = 0.f, a12 = 0.f, a22 = 0.f;
#pragma unroll
    for (int j = 0; j < 4; ++j) {
        const int l = lane * 4 + j;
        const float m = (l < len) ? 1.0f : 0.0f;
        const float dx = (px[j] - cx) * m;
        const float dy = (py[j] - cy) * m;
        const float dz = (pz[j] - cz) * m;
        a00 += dx * dx; a01 += dx * dy; a02 += dx * dz;
        a11 += dy * dy; a12 += dy * dz; a22 += dz * dz;
    }
#pragma unroll
    for (int off = 32; off >= 1; off >>= 1) {
        a00 += __shfl_xor(a00, off);
        a01 += __shfl_xor(a01, off);
        a02 += __shfl_xor(a02, off);
        a11 += __shfl_xor(a11, off);
        a12 += __shfl_xor(a12, off);
        a22 += __shfl_xor(a22, off);
    }

    // Analytic eigenvalues of symmetric 3x3 (double, redundant per-lane)
    const double A00 = a00, A01 = a01, A02 = a02, A11 = a11, A12 = a12, A22 = a22;
    const double q  = (A00 + A11 + A22) / 3.0;
    const double p1 = A01 * A01 + A02 * A02 + A12 * A12;
    const double d0 = A00 - q, d1 = A11 - q, d2 = A22 - q;
    const double p2 = d0 * d0 + d1 * d1 + d2 * d2 + 2.0 * p1;
    double w0, w1, w2;
    if (p2 <= 0.0) {
        w0 = w1 = w2 = q;
    } else {
        const double p  = sqrt(p2 / 6.0);
        const double ip = 1.0 / p;
        const double b00 = d0 * ip, b11 = d1 * ip, b22 = d2 * ip;
        const double b01 = A01 * ip, b02 = A02 * ip, b12 = A12 * ip;
        double detB = b00 * (b11 * b22 - b12 * b12)
                    - b01 * (b01 * b22 - b12 * b02)
                    + b02 * (b01 * b12 - b11 * b02);
        double r = 0.5 * detB;
        r = fmin(1.0, fmax(-1.0, r));
        const double phi = acos(r) / 3.0;
        w2 = q + 2.0 * p * cos(phi);
        w0 = q + 2.0 * p * cos(phi + 2.0943951023931953);  // +2pi/3
        w1 = 3.0 * q - w0 - w2;
    }
    const double dirwt = (w2 == 0.0) ? 0.0 : (1.0 - w1 / w2);

    // Top eigenvector: max-norm column of M = (A - w0 I)(A - w1 I)
    double vx = 0.0, vy = 0.0, vz = 0.0;
    {
        const double e00 = A00 - w0, e11 = A11 - w0, e22 = A22 - w0;
        const double f00 = A00 - w1, f11 = A11 - w1, f22 = A22 - w1;
        // column 0 of M = C0 * (f00, A01, A02)^T
        const double m0x = e00 * f00 + A01 * A01 + A02 * A02;
        const double m0y = A01 * f00 + e11 * A01 + A12 * A02;
        const double m0z = A02 * f00 + A12 * A01 + e22 * A02;
        // column 1
        const double m1x = e00 * A01 + A01 * f11 + A02 * A12;
        const double m1y = A01 * A01 + e11 * f11 + A12 * A12;
        const double m1z = A02 * A01 + A12 * f11 + e22 * A12;
        // column 2
        const double m2x = e00 * A02 + A01 * A12 + A02 * f22;
        const double m2y = A01 * A02 + e11 * A12 + A12 * f22;
        const double m2z = A02 * A02 + A12 * A12 + e22 * f22;
        const double n0 = m0x * m0x + m0y * m0y + m0z * m0z;
        const double n1 = m1x * m1x + m1y * m1y + m1z * m1z;
        const double n2 = m2x * m2x + m2y * m2y + m2z * m2z;
        double bx = m0x, by = m0y, bz = m0z, bn = n0;
        if (n1 > bn) { bx = m1x; by = m1y; bz = m1z; bn = n1; }
        if (n2 > bn) { bx = m2x; by = m2y; bz = m2z; bn = n2; }
        if (bn > 0.0) {
            const double is = 1.0 / sqrt(bn);
            vx = bx * is; vy = by * is; vz = bz * is;
        }
    }

    // Pass 3: sign correlate sc = sum(x0 * |xc - x0 v|)
    float v0x = (float)vx, v0y = (float)vy, v0z = (float)vz;
    float sc = 0.f;
#pragma unroll
    for (int j = 0; j < 4; ++j) {
        const int l = lane * 4 + j;
        const float m = (l < len) ? 1.0f : 0.0f;
        const float dx = (px[j] - cx) * m;
        const float dy = (py[j] - cy) * m;
        const float dz = (pz[j] - cz) * m;
        const float x0 = dx * v0x + dy * v0y + dz * v0z;
        const float ex = dx - x0 * v0x;
        const float ey = dy - x0 * v0y;
        const float ez = dz - x0 * v0z;
        const float sq = ex * ex + ey * ey + ez * ez;
        sc += x0 * sqrtf(sq) * m;
    }
#pragma unroll
    for (int off = 32; off >= 1; off >>= 1) sc += __shfl_xor(sc, off);

    if (sc < 0.f) { v0x = -v0x; v0y = -v0y; v0z = -v0z; }
    const float dwf = (float)dirwt;
    v0x *= dwf; v0y *= dwf; v0z *= dwf;

    if (lane == 0) {
        float* o = out + (size_t)c * 19;
        o[0] = cx; o[1] = cy; o[2] = cz;
        const float iw2 = (w2 != 0.0) ? (float)(1.0 / w2) : 0.0f;
        // B = A / w2 (exact recomposition since DELTA=0)
        o[3]  = a00 * iw2; o[4]  = a01 * iw2; o[5]  = a02 * iw2;
        o[6]  = a01 * iw2; o[7]  = a11 * iw2; o[8]  = a12 * iw2;
        o[9]  = a02 * iw2; o[10] = a12 * iw2; o[11] = a22 * iw2;
        o[12] = v0x; o[13] = v0y; o[14] = v0z;
        o[15] = fn;
        o[16] = mean_v; o[17] = std_v; o[18] = (float)mode;
    }
}

extern "C" void kernel_launch(void* const* d_in, const int* in_sizes, int n_in,
                              void* d_out, int out_size, void* d_ws, size_t ws_size,
                              hipStream_t stream) {
    const float* data      = (const float*)d_in[0];
    const int*   clust_idx = (const int*)d_in[1];
    const int*   clust_len = (const int*)d_in[2];
    float*       out       = (float*)d_out;
    clust_geo_kernel<<<NCLUST, 64, 0, stream>>>(data, clust_idx, clust_len, out);
}

// Round 2
// 166.802 us; speedup vs baseline: 1.0399x; 1.0399x over previous
//
#include <hip/hip_runtime.h>
#include <math.h>

#define NPTS   2000000
#define NCLUST 32768
#define CLEN   256

// ---------------------------------------------------------------------------
// Prepass: compress 6-float rows (24B) to 8B:
//   w.x = bf16(x) | bf16(y)<<16
//   w.y = bf16(z) | (sem<<13 | round(value*8191)) << 16
// ---------------------------------------------------------------------------
__device__ __forceinline__ unsigned int f32_to_bf16_rn(float f) {
    unsigned int u = __float_as_uint(f);
    unsigned int r = u + 0x7FFFu + ((u >> 16) & 1u);
    return r >> 16;
}

__global__ __launch_bounds__(256) void pack_kernel(
    const float* __restrict__ data, uint2* __restrict__ packed, int n)
{
    int i = blockIdx.x * 256 + threadIdx.x;
    const int stride = gridDim.x * 256;
    for (; i < n; i += stride) {
        const float* p = data + (size_t)i * 6;
        const float2 xy = *(const float2*)p;
        const float  z  = p[2];
        const float2 vs = *(const float2*)(p + 4);
        const unsigned int xb = f32_to_bf16_rn(xy.x);
        const unsigned int yb = f32_to_bf16_rn(xy.y);
        const unsigned int zb = f32_to_bf16_rn(z);
        int q = (int)(vs.x * 8191.0f + 0.5f);
        q = min(max(q, 0), 8191);
        const unsigned int s = (unsigned int)(int)vs.y;   // 0..4
        const unsigned int hi = (s << 13) | (unsigned int)q;
        packed[i] = make_uint2(xb | (yb << 16), zb | (hi << 16));
    }
}

// ---------------------------------------------------------------------------
// Main: one wave (64 lanes) per cluster, 4 clusters per 256-thread block.
// Single butterfly reduction of raw moments; analytic 3x3 eigen in double.
// ---------------------------------------------------------------------------
__global__ __launch_bounds__(256) void clust_geo_packed(
    const uint2* __restrict__ packed,    // N x 8B
    const int*   __restrict__ clust_idx, // C x 256
    const int*   __restrict__ clust_len, // C
    float*       __restrict__ out)       // C x 19
{
    const int wave = threadIdx.x >> 6;
    const int lane = threadIdx.x & 63;
    const int c    = blockIdx.x * 4 + wave;
    const int len  = clust_len[c];
    const float fn = (float)len;

    const int4 idx4 = ((const int4*)(clust_idx + (size_t)c * CLEN))[lane];
    const int idx[4] = {idx4.x, idx4.y, idx4.z, idx4.w};

    float px[4], py[4], pz[4];
    float sx = 0.f, sy = 0.f, sz = 0.f;
    float sxx = 0.f, sxy = 0.f, sxz = 0.f, syy = 0.f, syz = 0.f, szz = 0.f;
    float sv = 0.f, sv2 = 0.f;
    int pc0 = 0, pc1 = 0;   // c0|c1<<10|c2<<20 , c3|c4<<10

#pragma unroll
    for (int j = 0; j < 4; ++j) {
        const int l = lane * 4 + j;
        const bool ok = l < len;
        float x = 0.f, y = 0.f, z = 0.f, v = 0.f;
        int s = -1;
        if (ok) {
            const uint2 w = packed[idx[j]];
            x = __uint_as_float((w.x & 0xFFFF0000u) >> 16 << 16);
            x = __uint_as_float(w.x << 16);
            y = __uint_as_float(w.x & 0xFFFF0000u);
            z = __uint_as_float(w.y << 16);
            const unsigned int hi = w.y >> 16;
            s = (int)(hi >> 13);
            v = (float)(hi & 0x1FFFu) * (1.0f / 8191.0f);
        }
        px[j] = x; py[j] = y; pz[j] = z;
        sx += x; sy += y; sz += z;
        sxx += x * x; sxy += x * y; sxz += x * z;
        syy += y * y; syz += y * z; szz += z * z;
        sv += v; sv2 += v * v;
        pc0 += (s == 0) + ((s == 1) << 10) + ((s == 2) << 20);
        pc1 += (s == 3) + ((s == 4) << 10);
    }

#pragma unroll
    for (int off = 32; off >= 1; off >>= 1) {
        sx  += __shfl_xor(sx, off);
        sy  += __shfl_xor(sy, off);
        sz  += __shfl_xor(sz, off);
        sxx += __shfl_xor(sxx, off);
        sxy += __shfl_xor(sxy, off);
        sxz += __shfl_xor(sxz, off);
        syy += __shfl_xor(syy, off);
        syz += __shfl_xor(syz, off);
        szz += __shfl_xor(szz, off);
        sv  += __shfl_xor(sv, off);
        sv2 += __shfl_xor(sv2, off);
        pc0 += __shfl_xor(pc0, off);
        pc1 += __shfl_xor(pc1, off);
    }

    const float inv_n = 1.0f / fn;
    const float cx = sx * inv_n, cy = sy * inv_n, cz = sz * inv_n;
    const float mean_v = sv * inv_n;
    const float var_v = (sv2 - fn * mean_v * mean_v) / (fn - 1.0f);
    const float std_v = sqrtf(fmaxf(var_v, 0.0f));

    const int c0 = pc0 & 0x3FF, c1 = (pc0 >> 10) & 0x3FF, c2 = (pc0 >> 20) & 0x3FF;
    const int c3 = pc1 & 0x3FF, c4 = (pc1 >> 10) & 0x3FF;
    int mode = 0, best = c0;
    if (c1 > best) { best = c1; mode = 1; }
    if (c2 > best) { best = c2; mode = 2; }
    if (c3 > best) { best = c3; mode = 3; }
    if (c4 > best) { best = c4; mode = 4; }

    // covariance from raw moments
    const float a00 = sxx - fn * cx * cx;
    const float a01 = sxy - fn * cx * cy;
    const float a02 = sxz - fn * cx * cz;
    const float a11 = syy - fn * cy * cy;
    const float a12 = syz - fn * cy * cz;
    const float a22 = szz - fn * cz * cz;

    // Analytic eigenvalues (double, redundant per-lane)
    const double A00 = a00, A01 = a01, A02 = a02, A11 = a11, A12 = a12, A22 = a22;
    const double q  = (A00 + A11 + A22) / 3.0;
    const double p1 = A01 * A01 + A02 * A02 + A12 * A12;
    const double d0 = A00 - q, d1 = A11 - q, d2 = A22 - q;
    const double p2 = d0 * d0 + d1 * d1 + d2 * d2 + 2.0 * p1;
    double w0, w1, w2;
    if (p2 <= 0.0) {
        w0 = w1 = w2 = q;
    } else {
        const double p  = sqrt(p2 / 6.0);
        const double ip = 1.0 / p;
        const double b00 = d0 * ip, b11 = d1 * ip, b22 = d2 * ip;
        const double b01 = A01 * ip, b02 = A02 * ip, b12 = A12 * ip;
        double detB = b00 * (b11 * b22 - b12 * b12)
                    - b01 * (b01 * b22 - b12 * b02)
                    + b02 * (b01 * b12 - b11 * b02);
        double r = 0.5 * detB;
        r = fmin(1.0, fmax(-1.0, r));
        const double phi = acos(r) / 3.0;
        w2 = q + 2.0 * p * cos(phi);
        w0 = q + 2.0 * p * cos(phi + 2.0943951023931953);
        w1 = 3.0 * q - w0 - w2;
    }
    const double dirwt = (w2 == 0.0) ? 0.0 : (1.0 - w1 / w2);

    // Top eigenvector: max-norm column of (A - w0 I)(A - w1 I)
    double vx = 0.0, vy = 0.0, vz = 0.0;
    {
        const double e00 = A00 - w0, e11 = A11 - w0, e22 = A22 - w0;
        const double f00 = A00 - w1, f11 = A11 - w1, f22 = A22 - w1;
        const double m0x = e00 * f00 + A01 * A01 + A02 * A02;
        const double m0y = A01 * f00 + e11 * A01 + A12 * A02;
        const double m0z = A02 * f00 + A12 * A01 + e22 * A02;
        const double m1x = e00 * A01 + A01 * f11 + A02 * A12;
        const double m1y = A01 * A01 + e11 * f11 + A12 * A12;
        const double m1z = A02 * A01 + A12 * f11 + e22 * A12;
        const double m2x = e00 * A02 + A01 * A12 + A02 * f22;
        const double m2y = A01 * A02 + e11 * A12 + A12 * f22;
        const double m2z = A02 * A02 + A12 * A12 + e22 * f22;
        const double n0 = m0x * m0x + m0y * m0y + m0z * m0z;
        const double n1 = m1x * m1x + m1y * m1y + m1z * m1z;
        const double n2 = m2x * m2x + m2y * m2y + m2z * m2z;
        double bx = m0x, by = m0y, bz = m0z, bn = n0;
        if (n1 > bn) { bx = m1x; by = m1y; bz = m1z; bn = n1; }
        if (n2 > bn) { bx = m2x; by = m2y; bz = m2z; bn = n2; }
        if (bn > 0.0) {
            const double is = 1.0 / sqrt(bn);
            vx = bx * is; vy = by * is; vz = bz * is;
        }
    }

    float v0x = (float)vx, v0y = (float)vy, v0z = (float)vz;
    float sc = 0.f;
#pragma unroll
    for (int j = 0; j < 4; ++j) {
        const int l = lane * 4 + j;
        const float m = (l < len) ? 1.0f : 0.0f;
        const float dx = (px[j] - cx) * m;
        const float dy = (py[j] - cy) * m;
        const float dz = (pz[j] - cz) * m;
        const float x0 = dx * v0x + dy * v0y + dz * v0z;
        const float ex = dx - x0 * v0x;
        const float ey = dy - x0 * v0y;
        const float ez = dz - x0 * v0z;
        const float sq = ex * ex + ey * ey + ez * ez;
        sc += x0 * sqrtf(sq) * m;
    }
#pragma unroll
    for (int off = 32; off >= 1; off >>= 1) sc += __shfl_xor(sc, off);

    if (sc < 0.f) { v0x = -v0x; v0y = -v0y; v0z = -v0z; }
    const float dwf = (float)dirwt;
    v0x *= dwf; v0y *= dwf; v0z *= dwf;

    if (lane == 0) {
        float* o = out + (size_t)c * 19;
        o[0] = cx; o[1] = cy; o[2] = cz;
        const float iw2 = (w2 != 0.0) ? (float)(1.0 / w2) : 0.0f;
        o[3]  = a00 * iw2; o[4]  = a01 * iw2; o[5]  = a02 * iw2;
        o[6]  = a01 * iw2; o[7]  = a11 * iw2; o[8]  = a12 * iw2;
        o[9]  = a02 * iw2; o[10] = a12 * iw2; o[11] = a22 * iw2;
        o[12] = v0x; o[13] = v0y; o[14] = v0z;
        o[15] = fn;
        o[16] = mean_v; o[17] = std_v; o[18] = (float)mode;
    }
}

// ---------------------------------------------------------------------------
// Fallback (round-0 kernel, proven): direct fp32 gather, 1 wave/block
// ---------------------------------------------------------------------------
__global__ __launch_bounds__(64) void clust_geo_kernel(
    const float* __restrict__ data,
    const int*   __restrict__ clust_idx,
    const int*   __restrict__ clust_len,
    float*       __restrict__ out)
{
    const int c    = blockIdx.x;
    const int lane = threadIdx.x;
    const int len  = clust_len[c];
    const float fn = (float)len;

    const int4 idx4 = ((const int4*)(clust_idx + (size_t)c * CLEN))[lane];
    const int idx[4] = {idx4.x, idx4.y, idx4.z, idx4.w};

    float px[4], py[4], pz[4];
    float sx = 0.f, sy = 0.f, sz = 0.f, sv = 0.f, sv2 = 0.f;
    int c0 = 0, c1 = 0, c2 = 0, c3 = 0, c4 = 0;

#pragma unroll
    for (int j = 0; j < 4; ++j) {
        const int l = lane * 4 + j;
        const bool ok = l < len;
        float x = 0.f, y = 0.f, z = 0.f, v = 0.f;
        int s = -1;
        if (ok) {
            const float* p = data + (size_t)idx[j] * 6;
            const float2 xy = *(const float2*)p;
            const float  zz = p[2];
            const float2 vs = *(const float2*)(p + 4);
            x = xy.x; y = xy.y; z = zz; v = vs.x; s = (int)vs.y;
        }
        px[j] = x; py[j] = y; pz[j] = z;
        sx += x; sy += y; sz += z; sv += v; sv2 += v * v;
        c0 += (s == 0); c1 += (s == 1); c2 += (s == 2); c3 += (s == 3); c4 += (s == 4);
    }
#pragma unroll
    for (int off = 32; off >= 1; off >>= 1) {
        sx += __shfl_xor(sx, off); sy += __shfl_xor(sy, off); sz += __shfl_xor(sz, off);
        sv += __shfl_xor(sv, off); sv2 += __shfl_xor(sv2, off);
        c0 += __shfl_xor(c0, off); c1 += __shfl_xor(c1, off); c2 += __shfl_xor(c2, off);
        c3 += __shfl_xor(c3, off); c4 += __shfl_xor(c4, off);
    }
    const float inv_n = 1.0f / fn;
    const float cx = sx * inv_n, cy = sy * inv_n, cz = sz * inv_n;
    const float mean_v = sv * inv_n;
    const float var_v = (sv2 - fn * mean_v * mean_v) / (fn - 1.0f);
    const float std_v = sqrtf(fmaxf(var_v, 0.0f));
    int mode = 0, best = c0;
    if (c1 > best) { best = c1; mode = 1; }
    if (c2 > best) { best = c2; mode = 2; }
    if (c3 > best) { best = c3; mode = 3; }
    if (c4 > best) { best = c4; mode = 4; }

    float a00 = 0.f, a01 = 0.f, a02 = 0.f, a11 = 0.f, a12 = 0.f, a22 = 0.f;
#pragma unroll
    for (int j = 0; j < 4; ++j) {
        const int l = lane * 4 + j;
        const float m = (l < len) ? 1.0f : 0.0f;
        const float dx = (px[j] - cx) * m;
        const float dy = (py[j] - cy) * m;
        const float dz = (pz[j] - cz) * m;
        a00 += dx * dx; a01 += dx * dy; a02 += dx * dz;
        a11 += dy * dy; a12 += dy * dz; a22 += dz * dz;
    }
#pragma unroll
    for (int off = 32; off >= 1; off >>= 1) {
        a00 += __shfl_xor(a00, off); a01 += __shfl_xor(a01, off); a02 += __shfl_xor(a02, off);
        a11 += __shfl_xor(a11, off); a12 += __shfl_xor(a12, off); a22 += __shfl_xor(a22, off);
    }

    const double A00 = a00, A01 = a01, A02 = a02, A11 = a11, A12 = a12, A22 = a22;
    const double q  = (A00 + A11 + A22) / 3.0;
    const double p1 = A01 * A01 + A02 * A02 + A12 * A12;
    const double d0 = A00 - q, d1 = A11 - q, d2 = A22 - q;
    const double p2 = d0 * d0 + d1 * d1 + d2 * d2 + 2.0 * p1;
    double w0, w1, w2;
    if (p2 <= 0.0) { w0 = w1 = w2 = q; }
    else {
        const double p  = sqrt(p2 / 6.0);
        const double ip = 1.0 / p;
        const double b00 = d0 * ip, b11 = d1 * ip, b22 = d2 * ip;
        const double b01 = A01 * ip, b02 = A02 * ip, b12 = A12 * ip;
        double detB = b00 * (b11 * b22 - b12 * b12)
                    - b01 * (b01 * b22 - b12 * b02)
                    + b02 * (b01 * b12 - b11 * b02);
        double r = fmin(1.0, fmax(-1.0, 0.5 * detB));
        const double phi = acos(r) / 3.0;
        w2 = q + 2.0 * p * cos(phi);
        w0 = q + 2.0 * p * cos(phi + 2.0943951023931953);
        w1 = 3.0 * q - w0 - w2;
    }
    const double dirwt = (w2 == 0.0) ? 0.0 : (1.0 - w1 / w2);
    double vx = 0.0, vy = 0.0, vz = 0.0;
    {
        const double e00 = A00 - w0, e11 = A11 - w0, e22 = A22 - w0;
        const double f00 = A00 - w1, f11 = A11 - w1, f22 = A22 - w1;
        const double m0x = e00 * f00 + A01 * A01 + A02 * A02;
        const double m0y = A01 * f00 + e11 * A01 + A12 * A02;
        const double m0z = A02 * f00 + A12 * A01 + e22 * A02;
        const double m1x = e00 * A01 + A01 * f11 + A02 * A12;
        const double m1y = A01 * A01 + e11 * f11 + A12 * A12;
        const double m1z = A02 * A01 + A12 * f11 + e22 * A12;
        const double m2x = e00 * A02 + A01 * A12 + A02 * f22;
        const double m2y = A01 * A02 + e11 * A12 + A12 * f22;
        const double m2z = A02 * A02 + A12 * A12 + e22 * f22;
        const double n0 = m0x * m0x + m0y * m0y + m0z * m0z;
        const double n1 = m1x * m1x + m1y * m1y + m1z * m1z;
        const double n2 = m2x * m2x + m2y * m2y + m2z * m2z;
        double bx = m0x, by = m0y, bz = m0z, bn = n0;
        if (n1 > bn) { bx = m1x; by = m1y; bz = m1z; bn = n1; }
        if (n2 > bn) { bx = m2x; by = m2y; bz = m2z; bn = n2; }
        if (bn > 0.0) {
            const double is = 1.0 / sqrt(bn);
            vx = bx * is; vy = by * is; vz = bz * is;
        }
    }
    float v0x = (float)vx, v0y = (float)vy, v0z = (float)vz;
    float sc = 0.f;
#pragma unroll
    for (int j = 0; j < 4; ++j) {
        const int l = lane * 4 + j;
        const float m = (l < len) ? 1.0f : 0.0f;
        const float dx = (px[j] - cx) * m;
        const float dy = (py[j] - cy) * m;
        const float dz = (pz[j] - cz) * m;
        const float x0 = dx * v0x + dy * v0y + dz * v0z;
        const float ex = dx - x0 * v0x;
        const float ey = dy - x0 * v0y;
        const float ez = dz - x0 * v0z;
        sc += x0 * sqrtf(ex * ex + ey * ey + ez * ez) * m;
    }
#pragma unroll
    for (int off = 32; off >= 1; off >>= 1) sc += __shfl_xor(sc, off);
    if (sc < 0.f) { v0x = -v0x; v0y = -v0y; v0z = -v0z; }
    const float dwf = (float)dirwt;
    v0x *= dwf; v0y *= dwf; v0z *= dwf;

    if (lane == 0) {
        float* o = out + (size_t)c * 19;
        o[0] = cx; o[1] = cy; o[2] = cz;
        const float iw2 = (w2 != 0.0) ? (float)(1.0 / w2) : 0.0f;
        o[3]  = a00 * iw2; o[4]  = a01 * iw2; o[5]  = a02 * iw2;
        o[6]  = a01 * iw2; o[7]  = a11 * iw2; o[8]  = a12 * iw2;
        o[9]  = a02 * iw2; o[10] = a12 * iw2; o[11] = a22 * iw2;
        o[12] = v0x; o[13] = v0y; o[14] = v0z;
        o[15] = fn;
        o[16] = mean_v; o[17] = std_v; o[18] = (float)mode;
    }
}

extern "C" void kernel_launch(void* const* d_in, const int* in_sizes, int n_in,
                              void* d_out, int out_size, void* d_ws, size_t ws_size,
                              hipStream_t stream) {
    const float* data      = (const float*)d_in[0];
    const int*   clust_idx = (const int*)d_in[1];
    const int*   clust_len = (const int*)d_in[2];
    float*       out       = (float*)d_out;

    const size_t need = (size_t)NPTS * sizeof(uint2);
    if (ws_size >= need) {
        uint2* packed = (uint2*)d_ws;
        pack_kernel<<<2048, 256, 0, stream>>>(data, packed, NPTS);
        clust_geo_packed<<<NCLUST / 4, 256, 0, stream>>>(packed, clust_idx, clust_len, out);
    } else {
        clust_geo_kernel<<<NCLUST, 64, 0, stream>>>(data, clust_idx, clust_len, out);
    }
}